// Round 5
// baseline (228.478 us; speedup 1.0000x reference)
//
#include <hip/hip_runtime.h>
#include <math.h>

// ---------------------------------------------------------------------------
// SparseMHA, round 5:
//   hb = bf16(h)
//   qkv[n][768] bf16 = one fused MFMA GEMM (q scaled) ; LDS-staged 128x128
//   fused attn: no max-subtraction (|s|<~2), double-buffered co-issued
//               k+v gathers, one mem round-trip per 8-edge chunk
//   out = aggb @ Wo + bo (f32)
// ---------------------------------------------------------------------------

typedef __attribute__((ext_vector_type(8))) short bf16x8;
typedef __attribute__((ext_vector_type(4))) float f32x4;

__device__ __forceinline__ ushort f2bf(float f) {           // RNE f32->bf16
    uint u = __float_as_uint(f);
    u += 0x7fffu + ((u >> 16) & 1u);
    return (ushort)(u >> 16);
}
__device__ __forceinline__ float bflo(uint u) { return __uint_as_float(u << 16); }
__device__ __forceinline__ float bfhi(uint u) { return __uint_as_float(u & 0xffff0000u); }

__device__ __forceinline__ void load_lds16(const void* g, void* l) {
    __builtin_amdgcn_global_load_lds(
        (const __attribute__((address_space(1))) void*)g,
        (__attribute__((address_space(3))) void*)l, 16, 0, 0);
}

// f32 -> bf16 elementwise (h)
__global__ __launch_bounds__(256) void convert_bf16(
    const float* __restrict__ in, ushort* __restrict__ out, size_t nelem)
{
    size_t i = ((size_t)blockIdx.x * 256 + threadIdx.x) * 4;
    if (i >= nelem) return;
    float4 v = *(const float4*)(in + i);
    *(ushort4*)(out + i) = make_ushort4(f2bf(v.x), f2bf(v.y), f2bf(v.z), f2bf(v.w));
}

// Wq,Wk,Wv [256x256] f32 -> concat W^T bf16 [768][256]
__global__ __launch_bounds__(256) void convert_wt3(
    const float* __restrict__ Wq, const float* __restrict__ Wk,
    const float* __restrict__ Wv, ushort* __restrict__ Wall)
{
    int m = blockIdx.y;
    const float* W = m == 0 ? Wq : (m == 1 ? Wk : Wv);
    int idx = blockIdx.x * 256 + threadIdx.x;   // idx = k*256 + nn
    int k = idx >> 8, nn = idx & 255;
    Wall[((size_t)m * 256 + nn) * 256 + k] = f2bf(W[idx]);
}

__global__ __launch_bounds__(256) void convert_wt1(
    const float* __restrict__ W, ushort* __restrict__ Wt)
{
    int idx = blockIdx.x * 256 + threadIdx.x;
    int k = idx >> 8, nn = idx & 255;
    Wt[nn * 256 + k] = f2bf(W[idx]);
}

__global__ __launch_bounds__(256) void concat_bias(
    const float* __restrict__ bq, const float* __restrict__ bk,
    const float* __restrict__ bv, float* __restrict__ ball)
{
    int i = blockIdx.x * 256 + threadIdx.x;
    if (i >= 768) return;
    ball[i] = i < 256 ? bq[i] : (i < 512 ? bk[i - 256] : bv[i - 512]);
}

// ---------------------------------------------------------------------------
// LDS-staged MFMA GEMM (m97 structure), unchanged from round 4.
// ---------------------------------------------------------------------------
template<int MODE>
__global__ __launch_bounds__(256) void gemm_mfma_lds(
    const ushort* __restrict__ A, const ushort* __restrict__ Wt,
    const float* __restrict__ bias, ushort* __restrict__ qkv,
    float* __restrict__ outf, int n, float scale)
{
    __shared__ ushort As[128 * 64];
    __shared__ ushort Bs[128 * 64];

    const int nwg = gridDim.x * gridDim.y;
    const int orig = blockIdx.y * gridDim.x + blockIdx.x;
    const int xcd = orig & 7, rnd = orig >> 3;
    const int q8 = nwg >> 3, r8 = nwg & 7;
    const int wgid = (xcd < r8 ? xcd * (q8 + 1) : r8 * (q8 + 1) + (xcd - r8) * q8) + rnd;
    const int tx = wgid % gridDim.x;
    const int ty = wgid / gridDim.x;

    const int tid = threadIdx.x;
    const int lane = tid & 63;
    const int wave = tid >> 6;
    const int col0 = tx * 128;
    const int row0 = ty * 128;
    const int fr = lane & 15;
    const int kg = lane >> 4;
    const int wr = (wave >> 1) * 64;
    const int wc = (wave & 1) * 64;

    f32x4 acc[4][4] = {};

    const int srow = tid >> 3;
    const int sc8 = tid & 7;

    for (int kt = 0; kt < 4; ++kt) {
        #pragma unroll
        for (int it = 0; it < 4; ++it) {
            int r = srow + it * 32;
            int chunk = sc8 ^ (r & 7);
            int ar = row0 + r; ar = ar < n ? ar : n - 1;
            load_lds16((const char*)A + (size_t)ar * 512 + kt * 128 + chunk * 16,
                       (char*)As + (it * 256 + tid) * 16);
            load_lds16((const char*)Wt + (size_t)(col0 + r) * 512 + kt * 128 + chunk * 16,
                       (char*)Bs + (it * 256 + tid) * 16);
        }
        __syncthreads();

        #pragma unroll
        for (int ks = 0; ks < 2; ++ks) {
            bf16x8 a[4], b[4];
            #pragma unroll
            for (int i = 0; i < 4; ++i) {
                int r = wr + i * 16 + fr;
                int chunk = (ks * 4 + kg) ^ (r & 7);
                a[i] = *(const bf16x8*)((const char*)As + r * 128 + chunk * 16);
            }
            #pragma unroll
            for (int j = 0; j < 4; ++j) {
                int c = wc + j * 16 + fr;
                int chunk = (ks * 4 + kg) ^ (c & 7);
                b[j] = *(const bf16x8*)((const char*)Bs + c * 128 + chunk * 16);
            }
            #pragma unroll
            for (int i = 0; i < 4; ++i)
                #pragma unroll
                for (int j = 0; j < 4; ++j)
                    acc[i][j] = __builtin_amdgcn_mfma_f32_16x16x32_bf16(
                        a[i], b[j], acc[i][j], 0, 0, 0);
        }
        __syncthreads();
    }

    #pragma unroll
    for (int j = 0; j < 4; ++j) {
        int gcol = col0 + wc + j * 16 + fr;
        float bj = bias[gcol];
        float sc = (MODE == 0 && gcol < 256) ? scale : 1.f;
        #pragma unroll
        for (int i = 0; i < 4; ++i) {
            #pragma unroll
            for (int r = 0; r < 4; ++r) {
                int grow = row0 + wr + i * 16 + kg * 4 + r;
                if (grow >= n) continue;
                float val = (acc[i][j][r] + bj) * sc;
                if constexpr (MODE == 0)
                    qkv[(size_t)grow * 768 + gcol] = f2bf(val);
                else
                    outf[(size_t)grow * 256 + gcol] = val;
            }
        }
    }
}

// CSR row pointers from sorted row[]: row_ptr[i] = lower_bound(row, i)
__global__ __launch_bounds__(256) void build_row_ptr(
    const int* __restrict__ row, int* __restrict__ row_ptr, int n, int E)
{
    int i = blockIdx.x * 256 + threadIdx.x;
    if (i > n) return;
    int lo = 0, hi = E;
    while (lo < hi) {
        int mid = (lo + hi) >> 1;
        if (row[mid] < i) lo = mid + 1; else hi = mid;
    }
    row_ptr[i] = lo;
}

// Fused SDDMM + softmax + SpMM over qkv[n][768] bf16. One wave per dst node.
// No max-subtraction (|s| <~ 2: exp(m) cancels in p/denom exactly).
// Double-buffered chunks: {col, k, v} gathers for chunk i+1 issued while
// chunk i computes -> one memory round-trip per chunk in steady state.
__global__ __launch_bounds__(256, 3) void fused_attn(
    const ushort* __restrict__ qkv, const int* __restrict__ col,
    const int* __restrict__ row_ptr, ushort* __restrict__ agg, int n)
{
    int node = blockIdx.x * 4 + (threadIdx.x >> 6);
    if (node >= n) return;
    int lane = threadIdx.x & 63;
    int p0 = row_ptr[node], p1 = row_ptr[node + 1];

    const int slot = lane >> 3;   // score phase: edge slot
    const int sh   = lane & 7;    // score phase: head
    const int ah   = lane >> 3;   // accum phase: head
    const int aj   = lane & 7;    // accum phase: dim quad

    // q[node, sh, :] -> 32 floats
    float qf[32];
    {
        const uint4* qp = (const uint4*)(qkv + (size_t)node * 768 + sh * 32);
        #pragma unroll
        for (int i = 0; i < 4; ++i) {
            uint4 t = qp[i];
            qf[8*i+0] = bflo(t.x); qf[8*i+1] = bfhi(t.x);
            qf[8*i+2] = bflo(t.y); qf[8*i+3] = bfhi(t.y);
            qf[8*i+4] = bflo(t.z); qf[8*i+5] = bfhi(t.z);
            qf[8*i+6] = bflo(t.w); qf[8*i+7] = bfhi(t.w);
        }
    }

    float denom = 0.f;
    float acc0 = 0.f, acc1 = 0.f, acc2 = 0.f, acc3 = 0.f;

    uint4 kkA[4]; uint2 vvA[8];
    uint4 kkB[4]; uint2 vvB[8];

// Issue all gathers for the chunk at `base` (invalid slots clamp to row 0;
// their contribution is masked later by exp(-inf)=0).
#define ISSUE(base, kk, vv)                                                    \
    do {                                                                       \
        int e_ = (base) + slot;                                                \
        int src_ = (e_ < p1) ? col[e_] : 0;                                    \
        const uint4* kp_ = (const uint4*)(qkv + (size_t)src_ * 768 + 256 + sh * 32); \
        kk[0] = kp_[0]; kk[1] = kp_[1]; kk[2] = kp_[2]; kk[3] = kp_[3];        \
        _Pragma("unroll")                                                      \
        for (int ee_ = 0; ee_ < 8; ++ee_) {                                    \
            int sv_ = __shfl(src_, ee_ << 3);                                  \
            vv[ee_] = *(const uint2*)(qkv + (size_t)sv_ * 768 + 512 + ah * 32 + (aj << 2)); \
        }                                                                      \
    } while (0)

#define CONSUME(base, kk, vv)                                                  \
    do {                                                                       \
        float sacc_ = 0.f;                                                     \
        _Pragma("unroll")                                                      \
        for (int i_ = 0; i_ < 4; ++i_) {                                       \
            sacc_ += qf[8*i_+0] * bflo(kk[i_].x) + qf[8*i_+1] * bfhi(kk[i_].x);\
            sacc_ += qf[8*i_+2] * bflo(kk[i_].y) + qf[8*i_+3] * bfhi(kk[i_].y);\
            sacc_ += qf[8*i_+4] * bflo(kk[i_].z) + qf[8*i_+5] * bfhi(kk[i_].z);\
            sacc_ += qf[8*i_+6] * bflo(kk[i_].w) + qf[8*i_+7] * bfhi(kk[i_].w);\
        }                                                                      \
        float s_ = ((base) + slot < p1) ? sacc_ : -INFINITY;                   \
        _Pragma("unroll")                                                      \
        for (int ee_ = 0; ee_ < 8; ++ee_) {                                    \
            float se_ = __shfl(s_, (ee_ << 3) + ah);                           \
            float pe_ = __expf(se_);                                           \
            denom += pe_;                                                      \
            acc0 = fmaf(pe_, bflo(vv[ee_].x), acc0);                           \
            acc1 = fmaf(pe_, bfhi(vv[ee_].x), acc1);                           \
            acc2 = fmaf(pe_, bflo(vv[ee_].y), acc2);                           \
            acc3 = fmaf(pe_, bfhi(vv[ee_].y), acc3);                           \
        }                                                                      \
    } while (0)

    if (p0 < p1) {
        int base = p0;
        ISSUE(base, kkA, vvA);
        for (;;) {
            if (base + 8 < p1) ISSUE(base + 8, kkB, vvB);
            CONSUME(base, kkA, vvA);
            base += 8;
            if (base >= p1) break;
            if (base + 8 < p1) ISSUE(base + 8, kkA, vvA);
            CONSUME(base, kkB, vvB);
            base += 8;
            if (base >= p1) break;
        }
    }
#undef ISSUE
#undef CONSUME

    float inv = denom > 0.f ? 1.f / denom : 0.f;
    ushort4 o = make_ushort4(f2bf(acc0 * inv), f2bf(acc1 * inv),
                             f2bf(acc2 * inv), f2bf(acc3 * inv));
    *(ushort4*)(agg + (size_t)node * 256 + (lane << 2)) = o;
}

extern "C" void kernel_launch(void* const* d_in, const int* in_sizes, int n_in,
                              void* d_out, int out_size, void* d_ws, size_t ws_size,
                              hipStream_t stream)
{
    const float* h  = (const float*)d_in[0];
    const int*   row = (const int*)d_in[1];
    const int*   col = (const int*)d_in[2];
    const float* Wq = (const float*)d_in[3];
    const float* bq = (const float*)d_in[4];
    const float* Wk = (const float*)d_in[5];
    const float* bk = (const float*)d_in[6];
    const float* Wv = (const float*)d_in[7];
    const float* bv = (const float*)d_in[8];
    const float* Wo = (const float*)d_in[9];
    const float* bo = (const float*)d_in[10];
    float* out = (float*)d_out;

    const int n = in_sizes[0] / 256;
    const int E = in_sizes[1];
    const size_t NC = (size_t)n * 256;

    char* base = (char*)d_ws;
    ushort* qkvb = (ushort*)(base);                 // NC*3 ushort = NC*6 B
    ushort* hb   = (ushort*)(base + NC * 6);        // NC*2
    ushort* aggb = (ushort*)(base + NC * 8);        // NC*2
    ushort* Wall = (ushort*)(base + NC * 10);       // 768*256*2 = 384KB
    ushort* Wot  = Wall + 768 * 256;                // 128KB
    float*  ball = (float*)(Wot + 65536);           // 3KB
    int* row_ptr = (int*)(ball + 768);

    const float scaling = 0.17677669529663687f;  // 32^-0.5

    dim3 blk(256);
    convert_bf16<<<dim3((int)((NC / 4 + 255) / 256)), blk, 0, stream>>>(h, hb, NC);
    convert_wt3<<<dim3(256, 3), blk, 0, stream>>>(Wq, Wk, Wv, Wall);
    convert_wt1<<<dim3(256), blk, 0, stream>>>(Wo, Wot);
    concat_bias<<<dim3(3), blk, 0, stream>>>(bq, bk, bv, ball);
    build_row_ptr<<<dim3((n + 256) / 256), blk, 0, stream>>>(row, row_ptr, n, E);

    const int mtiles = (n + 127) / 128;
    gemm_mfma_lds<0><<<dim3(6, mtiles), blk, 0, stream>>>(
        hb, Wall, ball, qkvb, nullptr, n, scaling);

    fused_attn<<<dim3((n + 3) / 4), blk, 0, stream>>>(
        qkvb, col, row_ptr, aggb, n);

    gemm_mfma_lds<1><<<dim3(2, mtiles), blk, 0, stream>>>(
        aggb, Wot, bo, nullptr, out, n, 1.f);
}

// Round 6
// 228.022 us; speedup vs baseline: 1.0020x; 1.0020x over previous
//
#include <hip/hip_runtime.h>
#include <math.h>

// ---------------------------------------------------------------------------
// SparseMHA, round 6:
//   hb = bf16(h)
//   qkv[n][768] bf16 = one fused MFMA GEMM (q scaled) ; LDS-staged 128x128
//   fused attn: lane-local-p layout (slot x head x dimhalf), whole-row col
//               prefetch, depth-2 k/v pipeline, per-node slot reduction
//   out = aggb @ Wo + bo (f32)
// ---------------------------------------------------------------------------

typedef __attribute__((ext_vector_type(8))) short bf16x8;
typedef __attribute__((ext_vector_type(4))) float f32x4;

__device__ __forceinline__ ushort f2bf(float f) {           // RNE f32->bf16
    uint u = __float_as_uint(f);
    u += 0x7fffu + ((u >> 16) & 1u);
    return (ushort)(u >> 16);
}
__device__ __forceinline__ float bflo(uint u) { return __uint_as_float(u << 16); }
__device__ __forceinline__ float bfhi(uint u) { return __uint_as_float(u & 0xffff0000u); }

__device__ __forceinline__ void load_lds16(const void* g, void* l) {
    __builtin_amdgcn_global_load_lds(
        (const __attribute__((address_space(1))) void*)g,
        (__attribute__((address_space(3))) void*)l, 16, 0, 0);
}

// f32 -> bf16 elementwise (h)
__global__ __launch_bounds__(256) void convert_bf16(
    const float* __restrict__ in, ushort* __restrict__ out, size_t nelem)
{
    size_t i = ((size_t)blockIdx.x * 256 + threadIdx.x) * 4;
    if (i >= nelem) return;
    float4 v = *(const float4*)(in + i);
    *(ushort4*)(out + i) = make_ushort4(f2bf(v.x), f2bf(v.y), f2bf(v.z), f2bf(v.w));
}

// Wq,Wk,Wv [256x256] f32 -> concat W^T bf16 [768][256]
__global__ __launch_bounds__(256) void convert_wt3(
    const float* __restrict__ Wq, const float* __restrict__ Wk,
    const float* __restrict__ Wv, ushort* __restrict__ Wall)
{
    int m = blockIdx.y;
    const float* W = m == 0 ? Wq : (m == 1 ? Wk : Wv);
    int idx = blockIdx.x * 256 + threadIdx.x;   // idx = k*256 + nn
    int k = idx >> 8, nn = idx & 255;
    Wall[((size_t)m * 256 + nn) * 256 + k] = f2bf(W[idx]);
}

__global__ __launch_bounds__(256) void convert_wt1(
    const float* __restrict__ W, ushort* __restrict__ Wt)
{
    int idx = blockIdx.x * 256 + threadIdx.x;
    int k = idx >> 8, nn = idx & 255;
    Wt[nn * 256 + k] = f2bf(W[idx]);
}

__global__ __launch_bounds__(256) void concat_bias(
    const float* __restrict__ bq, const float* __restrict__ bk,
    const float* __restrict__ bv, float* __restrict__ ball)
{
    int i = blockIdx.x * 256 + threadIdx.x;
    if (i >= 768) return;
    ball[i] = i < 256 ? bq[i] : (i < 512 ? bk[i - 256] : bv[i - 512]);
}

// ---------------------------------------------------------------------------
// LDS-staged MFMA GEMM (m97 structure), unchanged.
// ---------------------------------------------------------------------------
template<int MODE>
__global__ __launch_bounds__(256) void gemm_mfma_lds(
    const ushort* __restrict__ A, const ushort* __restrict__ Wt,
    const float* __restrict__ bias, ushort* __restrict__ qkv,
    float* __restrict__ outf, int n, float scale)
{
    __shared__ ushort As[128 * 64];
    __shared__ ushort Bs[128 * 64];

    const int nwg = gridDim.x * gridDim.y;
    const int orig = blockIdx.y * gridDim.x + blockIdx.x;
    const int xcd = orig & 7, rnd = orig >> 3;
    const int q8 = nwg >> 3, r8 = nwg & 7;
    const int wgid = (xcd < r8 ? xcd * (q8 + 1) : r8 * (q8 + 1) + (xcd - r8) * q8) + rnd;
    const int tx = wgid % gridDim.x;
    const int ty = wgid / gridDim.x;

    const int tid = threadIdx.x;
    const int lane = tid & 63;
    const int wave = tid >> 6;
    const int col0 = tx * 128;
    const int row0 = ty * 128;
    const int fr = lane & 15;
    const int kg = lane >> 4;
    const int wr = (wave >> 1) * 64;
    const int wc = (wave & 1) * 64;

    f32x4 acc[4][4] = {};

    const int srow = tid >> 3;
    const int sc8 = tid & 7;

    for (int kt = 0; kt < 4; ++kt) {
        #pragma unroll
        for (int it = 0; it < 4; ++it) {
            int r = srow + it * 32;
            int chunk = sc8 ^ (r & 7);
            int ar = row0 + r; ar = ar < n ? ar : n - 1;
            load_lds16((const char*)A + (size_t)ar * 512 + kt * 128 + chunk * 16,
                       (char*)As + (it * 256 + tid) * 16);
            load_lds16((const char*)Wt + (size_t)(col0 + r) * 512 + kt * 128 + chunk * 16,
                       (char*)Bs + (it * 256 + tid) * 16);
        }
        __syncthreads();

        #pragma unroll
        for (int ks = 0; ks < 2; ++ks) {
            bf16x8 a[4], b[4];
            #pragma unroll
            for (int i = 0; i < 4; ++i) {
                int r = wr + i * 16 + fr;
                int chunk = (ks * 4 + kg) ^ (r & 7);
                a[i] = *(const bf16x8*)((const char*)As + r * 128 + chunk * 16);
            }
            #pragma unroll
            for (int j = 0; j < 4; ++j) {
                int c = wc + j * 16 + fr;
                int chunk = (ks * 4 + kg) ^ (c & 7);
                b[j] = *(const bf16x8*)((const char*)Bs + c * 128 + chunk * 16);
            }
            #pragma unroll
            for (int i = 0; i < 4; ++i)
                #pragma unroll
                for (int j = 0; j < 4; ++j)
                    acc[i][j] = __builtin_amdgcn_mfma_f32_16x16x32_bf16(
                        a[i], b[j], acc[i][j], 0, 0, 0);
        }
        __syncthreads();
    }

    #pragma unroll
    for (int j = 0; j < 4; ++j) {
        int gcol = col0 + wc + j * 16 + fr;
        float bj = bias[gcol];
        float sc = (MODE == 0 && gcol < 256) ? scale : 1.f;
        #pragma unroll
        for (int i = 0; i < 4; ++i) {
            #pragma unroll
            for (int r = 0; r < 4; ++r) {
                int grow = row0 + wr + i * 16 + kg * 4 + r;
                if (grow >= n) continue;
                float val = (acc[i][j][r] + bj) * sc;
                if constexpr (MODE == 0)
                    qkv[(size_t)grow * 768 + gcol] = f2bf(val);
                else
                    outf[(size_t)grow * 256 + gcol] = val;
            }
        }
    }
}

// CSR row pointers from sorted row[]: row_ptr[i] = lower_bound(row, i)
__global__ __launch_bounds__(256) void build_row_ptr(
    const int* __restrict__ row, int* __restrict__ row_ptr, int n, int E)
{
    int i = blockIdx.x * 256 + threadIdx.x;
    if (i > n) return;
    int lo = 0, hi = E;
    while (lo < hi) {
        int mid = (lo + hi) >> 1;
        if (row[mid] < i) lo = mid + 1; else hi = mid;
    }
    row_ptr[i] = lo;
}

// Fused SDDMM + softmax + SpMM over qkv[n][768] bf16. One wave per dst node.
// No max-subtraction (|s| small: exp(m) cancels exactly in p/denom).
// Lane map: slot = lane>>4 (4 edge slots), sh = (lane>>1)&7 (head),
//           hf = lane&1 (16-dim half). Each lane:
//   - half-dot q.k (16 elems) + shfl_xor(1) -> full score s, p = exp(s) LOCAL
//   - accumulates p * v[src, sh, hf*16..+16) into 16 f32 regs
// End of node: reduce acc/denom across 4 slots (shfl_xor 16,32), slot 0 stores.
// col for the whole node prefetched in ONE coalesced load -> every chunk's
// k/v gathers issue from register state with no memory-dependent waits.
__global__ __launch_bounds__(256) void fused_attn(
    const ushort* __restrict__ qkv, const int* __restrict__ col,
    const int* __restrict__ row_ptr, ushort* __restrict__ agg, int n)
{
    int node = blockIdx.x * 4 + (threadIdx.x >> 6);
    if (node >= n) return;
    int lane = threadIdx.x & 63;
    int p0 = row_ptr[node], p1 = row_ptr[node + 1];

    const int slot = lane >> 4;          // 0..3 edge slot
    const int qoff = (lane & 15) * 32;   // byte offset: sh*64 + hf*32

    // q[node, sh, hf*16 .. +16) -> 16 f32
    float qf[16];
    {
        const char* qb = (const char*)qkv + (size_t)node * 1536 + qoff;
        uint4 q0 = *(const uint4*)qb;
        uint4 q1 = *(const uint4*)(qb + 16);
        qf[0] = bflo(q0.x); qf[1] = bfhi(q0.x);
        qf[2] = bflo(q0.y); qf[3] = bfhi(q0.y);
        qf[4] = bflo(q0.z); qf[5] = bfhi(q0.z);
        qf[6] = bflo(q0.w); qf[7] = bfhi(q0.w);
        qf[8] = bflo(q1.x); qf[9] = bfhi(q1.x);
        qf[10] = bflo(q1.y); qf[11] = bfhi(q1.y);
        qf[12] = bflo(q1.z); qf[13] = bfhi(q1.z);
        qf[14] = bflo(q1.w); qf[15] = bfhi(q1.w);
    }

    float denom = 0.f;
    float acc[16] = {};

#define ISSUE(IDX, K0, K1, V0, V1)                                            \
    do {                                                                       \
        int src_ = __shfl(cl, (IDX));                                          \
        const char* b_ = (const char*)qkv + (size_t)src_ * 1536 + qoff;        \
        K0 = *(const uint4*)(b_ + 512);  K1 = *(const uint4*)(b_ + 528);       \
        V0 = *(const uint4*)(b_ + 1024); V1 = *(const uint4*)(b_ + 1040);      \
    } while (0)

#define CONSUME(VALID, K0, K1, V0, V1)                                         \
    do {                                                                       \
        float sp_ =                                                            \
            qf[0]*bflo(K0.x) + qf[1]*bfhi(K0.x) + qf[2]*bflo(K0.y) +           \
            qf[3]*bfhi(K0.y) + qf[4]*bflo(K0.z) + qf[5]*bfhi(K0.z) +           \
            qf[6]*bflo(K0.w) + qf[7]*bfhi(K0.w) + qf[8]*bflo(K1.x) +           \
            qf[9]*bfhi(K1.x) + qf[10]*bflo(K1.y) + qf[11]*bfhi(K1.y) +         \
            qf[12]*bflo(K1.z) + qf[13]*bfhi(K1.z) + qf[14]*bflo(K1.w) +        \
            qf[15]*bfhi(K1.w);                                                 \
        float s_ = sp_ + __shfl_xor(sp_, 1);                                   \
        float p_ = (VALID) ? __expf(s_) : 0.f;                                 \
        denom += p_;                                                           \
        acc[0]  = fmaf(p_, bflo(V0.x), acc[0]);                                \
        acc[1]  = fmaf(p_, bfhi(V0.x), acc[1]);                                \
        acc[2]  = fmaf(p_, bflo(V0.y), acc[2]);                                \
        acc[3]  = fmaf(p_, bfhi(V0.y), acc[3]);                                \
        acc[4]  = fmaf(p_, bflo(V0.z), acc[4]);                                \
        acc[5]  = fmaf(p_, bfhi(V0.z), acc[5]);                                \
        acc[6]  = fmaf(p_, bflo(V0.w), acc[6]);                                \
        acc[7]  = fmaf(p_, bfhi(V0.w), acc[7]);                                \
        acc[8]  = fmaf(p_, bflo(V1.x), acc[8]);                                \
        acc[9]  = fmaf(p_, bfhi(V1.x), acc[9]);                                \
        acc[10] = fmaf(p_, bflo(V1.y), acc[10]);                               \
        acc[11] = fmaf(p_, bfhi(V1.y), acc[11]);                               \
        acc[12] = fmaf(p_, bflo(V1.z), acc[12]);                               \
        acc[13] = fmaf(p_, bfhi(V1.z), acc[13]);                               \
        acc[14] = fmaf(p_, bflo(V1.w), acc[14]);                               \
        acc[15] = fmaf(p_, bfhi(V1.w), acc[15]);                               \
    } while (0)

    for (int bbase = p0; bbase < p1; bbase += 64) {
        int bd = min(64, p1 - bbase);          // edges in this batch
        int cl = (lane < bd) ? col[bbase + lane] : 0;   // one coalesced load
        int nch = (bd + 3) >> 2;

        uint4 kA0, kA1, vA0, vA1, kB0, kB1, vB0, vB1;
        ISSUE(slot, kA0, kA1, vA0, vA1);
        int c = 0;
        for (;;) {
            if (c + 1 < nch) ISSUE((c + 1) * 4 + slot, kB0, kB1, vB0, vB1);
            CONSUME(c * 4 + slot < bd, kA0, kA1, vA0, vA1);
            if (++c >= nch) break;
            if (c + 1 < nch) ISSUE((c + 1) * 4 + slot, kA0, kA1, vA0, vA1);
            CONSUME(c * 4 + slot < bd, kB0, kB1, vB0, vB1);
            if (++c >= nch) break;
        }
    }
#undef ISSUE
#undef CONSUME

    // reduce over the 4 slots (lane bits 4,5)
    #pragma unroll
    for (int i = 0; i < 16; ++i) {
        acc[i] += __shfl_xor(acc[i], 16);
        acc[i] += __shfl_xor(acc[i], 32);
    }
    denom += __shfl_xor(denom, 16);
    denom += __shfl_xor(denom, 32);

    if (slot == 0) {
        float inv = denom > 0.f ? 1.f / denom : 0.f;
        uint o[8];
        #pragma unroll
        for (int i = 0; i < 8; ++i)
            o[i] = (uint)f2bf(acc[2 * i] * inv) |
                   ((uint)f2bf(acc[2 * i + 1] * inv) << 16);
        char* ob = (char*)agg + (size_t)node * 512 + qoff;
        *(uint4*)ob        = make_uint4(o[0], o[1], o[2], o[3]);
        *(uint4*)(ob + 16) = make_uint4(o[4], o[5], o[6], o[7]);
    }
}

extern "C" void kernel_launch(void* const* d_in, const int* in_sizes, int n_in,
                              void* d_out, int out_size, void* d_ws, size_t ws_size,
                              hipStream_t stream)
{
    const float* h  = (const float*)d_in[0];
    const int*   row = (const int*)d_in[1];
    const int*   col = (const int*)d_in[2];
    const float* Wq = (const float*)d_in[3];
    const float* bq = (const float*)d_in[4];
    const float* Wk = (const float*)d_in[5];
    const float* bk = (const float*)d_in[6];
    const float* Wv = (const float*)d_in[7];
    const float* bv = (const float*)d_in[8];
    const float* Wo = (const float*)d_in[9];
    const float* bo = (const float*)d_in[10];
    float* out = (float*)d_out;

    const int n = in_sizes[0] / 256;
    const int E = in_sizes[1];
    const size_t NC = (size_t)n * 256;

    char* base = (char*)d_ws;
    ushort* qkvb = (ushort*)(base);                 // NC*3 ushort = NC*6 B
    ushort* hb   = (ushort*)(base + NC * 6);        // NC*2
    ushort* aggb = (ushort*)(base + NC * 8);        // NC*2
    ushort* Wall = (ushort*)(base + NC * 10);       // 768*256*2 = 384KB
    ushort* Wot  = Wall + 768 * 256;                // 128KB
    float*  ball = (float*)(Wot + 65536);           // 3KB
    int* row_ptr = (int*)(ball + 768);

    const float scaling = 0.17677669529663687f;  // 32^-0.5

    dim3 blk(256);
    convert_bf16<<<dim3((int)((NC / 4 + 255) / 256)), blk, 0, stream>>>(h, hb, NC);
    convert_wt3<<<dim3(256, 3), blk, 0, stream>>>(Wq, Wk, Wv, Wall);
    convert_wt1<<<dim3(256), blk, 0, stream>>>(Wo, Wot);
    concat_bias<<<dim3(3), blk, 0, stream>>>(bq, bk, bv, ball);
    build_row_ptr<<<dim3((n + 256) / 256), blk, 0, stream>>>(row, row_ptr, n, E);

    const int mtiles = (n + 127) / 128;
    gemm_mfma_lds<0><<<dim3(6, mtiles), blk, 0, stream>>>(
        hb, Wall, ball, qkvb, nullptr, n, scaling);

    fused_attn<<<dim3((n + 3) / 4), blk, 0, stream>>>(
        qkvb, col, row_ptr, aggb, n);

    gemm_mfma_lds<1><<<dim3(2, mtiles), blk, 0, stream>>>(
        aggb, Wot, bo, nullptr, out, n, 1.f);
}

// Round 8
// 199.418 us; speedup vs baseline: 1.1457x; 1.1434x over previous
//
#include <hip/hip_runtime.h>
#include <math.h>

// ---------------------------------------------------------------------------
// SparseMHA, round 8:
//   hb = bf16(h)
//   one fused MFMA GEMM -> qb[n][256] bf16 (scaled q),
//                          kv[n] rows of 768B: k fp8 e4m3 (256B) + v bf16 (512B)
//   fused attn: gathers 768B/edge (was 1KB), lane-local p, whole-row col
//               prefetch, depth-2 pipeline
//   out = aggb @ Wo + bo (f32)
// ---------------------------------------------------------------------------

typedef __attribute__((ext_vector_type(8))) short bf16x8;
typedef __attribute__((ext_vector_type(4))) float f32x4;
typedef __attribute__((ext_vector_type(2))) float f32x2;

__device__ __forceinline__ ushort f2bf(float f) {           // RNE f32->bf16
    uint u = __float_as_uint(f);
    u += 0x7fffu + ((u >> 16) & 1u);
    return (ushort)(u >> 16);
}
__device__ __forceinline__ float bflo(uint u) { return __uint_as_float(u << 16); }
__device__ __forceinline__ float bfhi(uint u) { return __uint_as_float(u & 0xffff0000u); }

// fp8 e4m3 (OCP on gfx950) pack/unpack
__device__ __forceinline__ uchar f2fp8(float f) {
    return (uchar)(__builtin_amdgcn_cvt_pk_fp8_f32(f, f, 0, false) & 0xff);
}
__device__ __forceinline__ void fp8x4_to_f32(uint u, float* f) {
    f32x2 lo = __builtin_amdgcn_cvt_pk_f32_fp8(u, false);
    f32x2 hi = __builtin_amdgcn_cvt_pk_f32_fp8(u, true);
    f[0] = lo[0]; f[1] = lo[1]; f[2] = hi[0]; f[3] = hi[1];
}

__device__ __forceinline__ void load_lds16(const void* g, void* l) {
    __builtin_amdgcn_global_load_lds(
        (const __attribute__((address_space(1))) void*)g,
        (__attribute__((address_space(3))) void*)l, 16, 0, 0);
}

// f32 -> bf16 elementwise (h)
__global__ __launch_bounds__(256) void convert_bf16(
    const float* __restrict__ in, ushort* __restrict__ out, size_t nelem)
{
    size_t i = ((size_t)blockIdx.x * 256 + threadIdx.x) * 4;
    if (i >= nelem) return;
    float4 v = *(const float4*)(in + i);
    *(ushort4*)(out + i) = make_ushort4(f2bf(v.x), f2bf(v.y), f2bf(v.z), f2bf(v.w));
}

// All weight prep in one launch: grid (257, 4).
//  x<256: convert W_m (m=0..2 -> Wall concat, m=3 -> Wot), transposed, bf16
//  x==256, m<3: bias concat
__global__ __launch_bounds__(256) void prep_w(
    const float* __restrict__ Wq, const float* __restrict__ Wk,
    const float* __restrict__ Wv, const float* __restrict__ Wo,
    const float* __restrict__ bq, const float* __restrict__ bk,
    const float* __restrict__ bv,
    ushort* __restrict__ Wall, ushort* __restrict__ Wot,
    float* __restrict__ ball)
{
    int m = blockIdx.y;
    if (blockIdx.x < 256) {
        int idx = blockIdx.x * 256 + threadIdx.x;   // idx = k*256 + nn
        int k = idx >> 8, nn = idx & 255;
        if (m < 3) {
            const float* W = m == 0 ? Wq : (m == 1 ? Wk : Wv);
            Wall[((size_t)m * 256 + nn) * 256 + k] = f2bf(W[idx]);
        } else {
            Wot[nn * 256 + k] = f2bf(Wo[idx]);
        }
    } else if (m < 3) {
        int i = threadIdx.x;
        ball[m * 256 + i] = (m == 0 ? bq : (m == 1 ? bk : bv))[i];
    }
}

// ---------------------------------------------------------------------------
// LDS-staged MFMA GEMM (m97 structure).
// MODE 0: cols [0,256) -> qb bf16 (scaled); [256,512) -> kv row k fp8;
//         [512,768) -> kv row v bf16 (row stride 768B). MODE 1: f32 out.
// ---------------------------------------------------------------------------
template<int MODE>
__global__ __launch_bounds__(256) void gemm_mfma_lds(
    const ushort* __restrict__ A, const ushort* __restrict__ Wt,
    const float* __restrict__ bias, ushort* __restrict__ qb,
    uchar* __restrict__ kv, float* __restrict__ outf, int n, float scale)
{
    __shared__ ushort As[128 * 64];
    __shared__ ushort Bs[128 * 64];

    const int nwg = gridDim.x * gridDim.y;
    const int orig = blockIdx.y * gridDim.x + blockIdx.x;
    const int xcd = orig & 7, rnd = orig >> 3;
    const int q8 = nwg >> 3, r8 = nwg & 7;
    const int wgid = (xcd < r8 ? xcd * (q8 + 1) : r8 * (q8 + 1) + (xcd - r8) * q8) + rnd;
    const int tx = wgid % gridDim.x;
    const int ty = wgid / gridDim.x;

    const int tid = threadIdx.x;
    const int lane = tid & 63;
    const int wave = tid >> 6;
    const int col0 = tx * 128;
    const int row0 = ty * 128;
    const int fr = lane & 15;
    const int kg = lane >> 4;
    const int wr = (wave >> 1) * 64;
    const int wc = (wave & 1) * 64;

    f32x4 acc[4][4] = {};

    const int srow = tid >> 3;
    const int sc8 = tid & 7;

    for (int kt = 0; kt < 4; ++kt) {
        #pragma unroll
        for (int it = 0; it < 4; ++it) {
            int r = srow + it * 32;
            int chunk = sc8 ^ (r & 7);
            int ar = row0 + r; ar = ar < n ? ar : n - 1;
            load_lds16((const char*)A + (size_t)ar * 512 + kt * 128 + chunk * 16,
                       (char*)As + (it * 256 + tid) * 16);
            load_lds16((const char*)Wt + (size_t)(col0 + r) * 512 + kt * 128 + chunk * 16,
                       (char*)Bs + (it * 256 + tid) * 16);
        }
        __syncthreads();

        #pragma unroll
        for (int ks = 0; ks < 2; ++ks) {
            bf16x8 a[4], b[4];
            #pragma unroll
            for (int i = 0; i < 4; ++i) {
                int r = wr + i * 16 + fr;
                int chunk = (ks * 4 + kg) ^ (r & 7);
                a[i] = *(const bf16x8*)((const char*)As + r * 128 + chunk * 16);
            }
            #pragma unroll
            for (int j = 0; j < 4; ++j) {
                int c = wc + j * 16 + fr;
                int chunk = (ks * 4 + kg) ^ (c & 7);
                b[j] = *(const bf16x8*)((const char*)Bs + c * 128 + chunk * 16);
            }
            #pragma unroll
            for (int i = 0; i < 4; ++i)
                #pragma unroll
                for (int j = 0; j < 4; ++j)
                    acc[i][j] = __builtin_amdgcn_mfma_f32_16x16x32_bf16(
                        a[i], b[j], acc[i][j], 0, 0, 0);
        }
        __syncthreads();
    }

    #pragma unroll
    for (int j = 0; j < 4; ++j) {
        int gcol = col0 + wc + j * 16 + fr;
        float bj = bias[gcol];
        float sc = (MODE == 0 && gcol < 256) ? scale : 1.f;
        #pragma unroll
        for (int i = 0; i < 4; ++i) {
            #pragma unroll
            for (int r = 0; r < 4; ++r) {
                int grow = row0 + wr + i * 16 + kg * 4 + r;
                if (grow >= n) continue;
                float val = (acc[i][j][r] + bj) * sc;
                if constexpr (MODE == 0) {
                    if (gcol < 256)
                        qb[(size_t)grow * 256 + gcol] = f2bf(val);
                    else if (gcol < 512)
                        kv[(size_t)grow * 768 + (gcol - 256)] = f2fp8(val);
                    else
                        *(ushort*)(kv + (size_t)grow * 768 + 256 +
                                   (size_t)(gcol - 512) * 2) = f2bf(val);
                } else {
                    outf[(size_t)grow * 256 + gcol] = val;
                }
            }
        }
    }
}

// CSR row pointers from sorted row[]: row_ptr[i] = lower_bound(row, i)
__global__ __launch_bounds__(256) void build_row_ptr(
    const int* __restrict__ row, int* __restrict__ row_ptr, int n, int E)
{
    int i = blockIdx.x * 256 + threadIdx.x;
    if (i > n) return;
    int lo = 0, hi = E;
    while (lo < hi) {
        int mid = (lo + hi) >> 1;
        if (row[mid] < i) lo = mid + 1; else hi = mid;
    }
    row_ptr[i] = lo;
}

// Fused SDDMM + softmax + SpMM. One wave per dst node.
// kv row (768B): k fp8 e4m3 [0,256) + v bf16 [256,768).
// Lane map: slot = lane>>4 (4 edge slots), l16 = lane&15 = (head, dim-half):
//   each lane covers 16 consecutive dims: 16B k load + 32B v load.
// Half-dot + shfl_xor(1) -> score; p = exp(s) lane-local (no max: |s|<~2).
// Per-node slot reduction at the end; one coalesced col load per 64 edges.
__global__ __launch_bounds__(256) void fused_attn(
    const ushort* __restrict__ qb, const uchar* __restrict__ kv,
    const int* __restrict__ col, const int* __restrict__ row_ptr,
    ushort* __restrict__ agg, int n)
{
    int node = blockIdx.x * 4 + (threadIdx.x >> 6);
    if (node >= n) return;
    int lane = threadIdx.x & 63;
    int p0 = row_ptr[node], p1 = row_ptr[node + 1];

    const int slot = lane >> 4;          // 0..3 edge slot
    const int l16 = lane & 15;           // (head, half) index
    const int qoff = l16 * 32;           // byte offset into 512B bf16 q row

    // q[node, 16 dims] -> 16 f32
    float qf[16];
    {
        const char* qbp = (const char*)qb + (size_t)node * 512 + qoff;
        uint4 q0 = *(const uint4*)qbp;
        uint4 q1 = *(const uint4*)(qbp + 16);
        qf[0] = bflo(q0.x); qf[1] = bfhi(q0.x);
        qf[2] = bflo(q0.y); qf[3] = bfhi(q0.y);
        qf[4] = bflo(q0.z); qf[5] = bfhi(q0.z);
        qf[6] = bflo(q0.w); qf[7] = bfhi(q0.w);
        qf[8] = bflo(q1.x); qf[9] = bfhi(q1.x);
        qf[10] = bflo(q1.y); qf[11] = bfhi(q1.y);
        qf[12] = bflo(q1.z); qf[13] = bfhi(q1.z);
        qf[14] = bflo(q1.w); qf[15] = bfhi(q1.w);
    }

    float denom = 0.f;
    float acc[16] = {};

#define ISSUE(IDX, K, V0, V1)                                                  \
    do {                                                                       \
        int src_ = __shfl(cl, (IDX));                                          \
        const char* b_ = (const char*)kv + (size_t)src_ * 768;                 \
        K  = *(const uint4*)(b_ + l16 * 16);                                   \
        V0 = *(const uint4*)(b_ + 256 + l16 * 32);                             \
        V1 = *(const uint4*)(b_ + 272 + l16 * 32);                             \
    } while (0)

#define CONSUME(VALID, K, V0, V1)                                              \
    do {                                                                       \
        float kf_[16];                                                         \
        fp8x4_to_f32(K.x, kf_); fp8x4_to_f32(K.y, kf_ + 4);                    \
        fp8x4_to_f32(K.z, kf_ + 8); fp8x4_to_f32(K.w, kf_ + 12);               \
        float sp_ = 0.f;                                                       \
        _Pragma("unroll")                                                      \
        for (int i_ = 0; i_ < 16; ++i_) sp_ = fmaf(qf[i_], kf_[i_], sp_);      \
        float s_ = sp_ + __shfl_xor(sp_, 1);                                   \
        float p_ = (VALID) ? __expf(s_) : 0.f;                                 \
        denom += p_;                                                           \
        acc[0]  = fmaf(p_, bflo(V0.x), acc[0]);                                \
        acc[1]  = fmaf(p_, bfhi(V0.x), acc[1]);                                \
        acc[2]  = fmaf(p_, bflo(V0.y), acc[2]);                                \
        acc[3]  = fmaf(p_, bfhi(V0.y), acc[3]);                                \
        acc[4]  = fmaf(p_, bflo(V0.z), acc[4]);                                \
        acc[5]  = fmaf(p_, bfhi(V0.z), acc[5]);                                \
        acc[6]  = fmaf(p_, bflo(V0.w), acc[6]);                                \
        acc[7]  = fmaf(p_, bfhi(V0.w), acc[7]);                                \
        acc[8]  = fmaf(p_, bflo(V1.x), acc[8]);                                \
        acc[9]  = fmaf(p_, bfhi(V1.x), acc[9]);                                \
        acc[10] = fmaf(p_, bflo(V1.y), acc[10]);                               \
        acc[11] = fmaf(p_, bfhi(V1.y), acc[11]);                               \
        acc[12] = fmaf(p_, bflo(V1.z), acc[12]);                               \
        acc[13] = fmaf(p_, bfhi(V1.z), acc[13]);                               \
        acc[14] = fmaf(p_, bflo(V1.w), acc[14]);                               \
        acc[15] = fmaf(p_, bfhi(V1.w), acc[15]);                               \
    } while (0)

    for (int bbase = p0; bbase < p1; bbase += 64) {
        int bd = min(64, p1 - bbase);          // edges in this batch
        int cl = (lane < bd) ? col[bbase + lane] : 0;   // one coalesced load
        int nch = (bd + 3) >> 2;

        uint4 kA, vA0, vA1, kB, vB0, vB1;
        ISSUE(slot, kA, vA0, vA1);
        int c = 0;
        for (;;) {
            if (c + 1 < nch) ISSUE((c + 1) * 4 + slot, kB, vB0, vB1);
            CONSUME(c * 4 + slot < bd, kA, vA0, vA1);
            if (++c >= nch) break;
            if (c + 1 < nch) ISSUE((c + 1) * 4 + slot, kA, vA0, vA1);
            CONSUME(c * 4 + slot < bd, kB, vB0, vB1);
            if (++c >= nch) break;
        }
    }
#undef ISSUE
#undef CONSUME

    // reduce over the 4 slots (lane bits 4,5)
    #pragma unroll
    for (int i = 0; i < 16; ++i) {
        acc[i] += __shfl_xor(acc[i], 16);
        acc[i] += __shfl_xor(acc[i], 32);
    }
    denom += __shfl_xor(denom, 16);
    denom += __shfl_xor(denom, 32);

    if (slot == 0) {
        float inv = denom > 0.f ? 1.f / denom : 0.f;
        uint o[8];
        #pragma unroll
        for (int i = 0; i < 8; ++i)
            o[i] = (uint)f2bf(acc[2 * i] * inv) |
                   ((uint)f2bf(acc[2 * i + 1] * inv) << 16);
        char* ob = (char*)agg + (size_t)node * 512 + qoff;
        *(uint4*)ob        = make_uint4(o[0], o[1], o[2], o[3]);
        *(uint4*)(ob + 16) = make_uint4(o[4], o[5], o[6], o[7]);
    }
}

extern "C" void kernel_launch(void* const* d_in, const int* in_sizes, int n_in,
                              void* d_out, int out_size, void* d_ws, size_t ws_size,
                              hipStream_t stream)
{
    const float* h  = (const float*)d_in[0];
    const int*   row = (const int*)d_in[1];
    const int*   col = (const int*)d_in[2];
    const float* Wq = (const float*)d_in[3];
    const float* bq = (const float*)d_in[4];
    const float* Wk = (const float*)d_in[5];
    const float* bk = (const float*)d_in[6];
    const float* Wv = (const float*)d_in[7];
    const float* bv = (const float*)d_in[8];
    const float* Wo = (const float*)d_in[9];
    const float* bo = (const float*)d_in[10];
    float* out = (float*)d_out;

    const int n = in_sizes[0] / 256;
    const int E = in_sizes[1];
    const size_t NC = (size_t)n * 256;

    char* base = (char*)d_ws;
    ushort* qbb  = (ushort*)(base);                 // NC*2 B
    uchar*  kv   = (uchar*)(base + NC * 2);         // n*768 B
    ushort* hb   = (ushort*)(base + NC * 2 + (size_t)n * 768);   // NC*2
    ushort* aggb = (ushort*)(base + NC * 4 + (size_t)n * 768);   // NC*2
    ushort* Wall = (ushort*)(base + NC * 6 + (size_t)n * 768);   // 384KB
    ushort* Wot  = Wall + 768 * 256;                // 128KB
    float*  ball = (float*)(Wot + 65536);           // 3KB
    int* row_ptr = (int*)(ball + 768);

    const float scaling = 0.17677669529663687f;  // 32^-0.5

    dim3 blk(256);
    convert_bf16<<<dim3((int)((NC / 4 + 255) / 256)), blk, 0, stream>>>(h, hb, NC);
    prep_w<<<dim3(257, 4), blk, 0, stream>>>(Wq, Wk, Wv, Wo, bq, bk, bv,
                                             Wall, Wot, ball);
    build_row_ptr<<<dim3((n + 256) / 256), blk, 0, stream>>>(row, row_ptr, n, E);

    const int mtiles = (n + 127) / 128;
    gemm_mfma_lds<0><<<dim3(6, mtiles), blk, 0, stream>>>(
        hb, Wall, ball, qbb, kv, nullptr, n, scaling);

    fused_attn<<<dim3((n + 3) / 4), blk, 0, stream>>>(
        qbb, kv, col, row_ptr, aggb, n);

    gemm_mfma_lds<1><<<dim3(2, mtiles), blk, 0, stream>>>(
        aggb, Wot, bo, nullptr, nullptr, out, n, 1.f);
}

// Round 9
// 175.748 us; speedup vs baseline: 1.3000x; 1.1347x over previous
//
#include <hip/hip_runtime.h>
#include <math.h>

// ---------------------------------------------------------------------------
// SparseMHA, round 9:
//   hb = bf16(h)
//   one fused MFMA GEMM -> qb[n][256] bf16 (scaled q),
//                          kv[n] rows of 768B: k fp8 e4m3 (256B) + v bf16 (512B)
//     epilogue: pack into LDS (XOR unit swizzle), coalesced 256B row bursts
//   fused attn: gathers 768B/edge, lane-local p, whole-row col prefetch,
//               depth-2 pipeline
//   out = aggb @ Wo + bo (f32)
// ---------------------------------------------------------------------------

typedef __attribute__((ext_vector_type(8))) short bf16x8;
typedef __attribute__((ext_vector_type(4))) float f32x4;
typedef __attribute__((ext_vector_type(2))) float f32x2;

__device__ __forceinline__ ushort f2bf(float f) {           // RNE f32->bf16
    uint u = __float_as_uint(f);
    u += 0x7fffu + ((u >> 16) & 1u);
    return (ushort)(u >> 16);
}
__device__ __forceinline__ float bflo(uint u) { return __uint_as_float(u << 16); }
__device__ __forceinline__ float bfhi(uint u) { return __uint_as_float(u & 0xffff0000u); }

// fp8 e4m3 (OCP on gfx950) pack/unpack
__device__ __forceinline__ uchar f2fp8(float f) {
    return (uchar)(__builtin_amdgcn_cvt_pk_fp8_f32(f, f, 0, false) & 0xff);
}
__device__ __forceinline__ void fp8x4_to_f32(uint u, float* f) {
    f32x2 lo = __builtin_amdgcn_cvt_pk_f32_fp8(u, false);
    f32x2 hi = __builtin_amdgcn_cvt_pk_f32_fp8(u, true);
    f[0] = lo[0]; f[1] = lo[1]; f[2] = hi[0]; f[3] = hi[1];
}

__device__ __forceinline__ void load_lds16(const void* g, void* l) {
    __builtin_amdgcn_global_load_lds(
        (const __attribute__((address_space(1))) void*)g,
        (__attribute__((address_space(3))) void*)l, 16, 0, 0);
}

// f32 -> bf16 elementwise (h)
__global__ __launch_bounds__(256) void convert_bf16(
    const float* __restrict__ in, ushort* __restrict__ out, size_t nelem)
{
    size_t i = ((size_t)blockIdx.x * 256 + threadIdx.x) * 4;
    if (i >= nelem) return;
    float4 v = *(const float4*)(in + i);
    *(ushort4*)(out + i) = make_ushort4(f2bf(v.x), f2bf(v.y), f2bf(v.z), f2bf(v.w));
}

// All weight prep in one launch: grid (257, 4).
__global__ __launch_bounds__(256) void prep_w(
    const float* __restrict__ Wq, const float* __restrict__ Wk,
    const float* __restrict__ Wv, const float* __restrict__ Wo,
    const float* __restrict__ bq, const float* __restrict__ bk,
    const float* __restrict__ bv,
    ushort* __restrict__ Wall, ushort* __restrict__ Wot,
    float* __restrict__ ball)
{
    int m = blockIdx.y;
    if (blockIdx.x < 256) {
        int idx = blockIdx.x * 256 + threadIdx.x;   // idx = k*256 + nn
        int k = idx >> 8, nn = idx & 255;
        if (m < 3) {
            const float* W = m == 0 ? Wq : (m == 1 ? Wk : Wv);
            Wall[((size_t)m * 256 + nn) * 256 + k] = f2bf(W[idx]);
        } else {
            Wot[nn * 256 + k] = f2bf(Wo[idx]);
        }
    } else if (m < 3) {
        int i = threadIdx.x;
        ball[m * 256 + i] = (m == 0 ? bq : (m == 1 ? bk : bv))[i];
    }
}

// ---------------------------------------------------------------------------
// LDS-staged MFMA GEMM (m97 structure).
// MODE 0: cols [0,256) -> qb bf16 (scaled); [256,512) -> kv k fp8;
//         [512,768) -> kv v bf16 (row stride 768B). Epilogue via LDS bounce.
// MODE 1: f32 out, direct coalesced stores.
// ---------------------------------------------------------------------------
template<int MODE>
__global__ __launch_bounds__(256) void gemm_mfma_lds(
    const ushort* __restrict__ A, const ushort* __restrict__ Wt,
    const float* __restrict__ bias, ushort* __restrict__ qb,
    uchar* __restrict__ kv, float* __restrict__ outf, int n, float scale)
{
    __shared__ ushort SH[2 * 128 * 64];          // As | Bs, reused by epilogue
    ushort* As = SH;
    ushort* Bs = SH + 128 * 64;

    const int nwg = gridDim.x * gridDim.y;
    const int orig = blockIdx.y * gridDim.x + blockIdx.x;
    const int xcd = orig & 7, rnd = orig >> 3;
    const int q8 = nwg >> 3, r8 = nwg & 7;
    const int wgid = (xcd < r8 ? xcd * (q8 + 1) : r8 * (q8 + 1) + (xcd - r8) * q8) + rnd;
    const int tx = wgid % gridDim.x;
    const int ty = wgid / gridDim.x;

    const int tid = threadIdx.x;
    const int lane = tid & 63;
    const int wave = tid >> 6;
    const int col0 = tx * 128;
    const int row0 = ty * 128;
    const int fr = lane & 15;
    const int kg = lane >> 4;
    const int wr = (wave >> 1) * 64;
    const int wc = (wave & 1) * 64;

    f32x4 acc[4][4] = {};

    const int srow = tid >> 3;
    const int sc8 = tid & 7;

    for (int kt = 0; kt < 4; ++kt) {
        #pragma unroll
        for (int it = 0; it < 4; ++it) {
            int r = srow + it * 32;
            int chunk = sc8 ^ (r & 7);
            int ar = row0 + r; ar = ar < n ? ar : n - 1;
            load_lds16((const char*)A + (size_t)ar * 512 + kt * 128 + chunk * 16,
                       (char*)As + (it * 256 + tid) * 16);
            load_lds16((const char*)Wt + (size_t)(col0 + r) * 512 + kt * 128 + chunk * 16,
                       (char*)Bs + (it * 256 + tid) * 16);
        }
        __syncthreads();

        #pragma unroll
        for (int ks = 0; ks < 2; ++ks) {
            bf16x8 a[4], b[4];
            #pragma unroll
            for (int i = 0; i < 4; ++i) {
                int r = wr + i * 16 + fr;
                int chunk = (ks * 4 + kg) ^ (r & 7);
                a[i] = *(const bf16x8*)((const char*)As + r * 128 + chunk * 16);
            }
            #pragma unroll
            for (int j = 0; j < 4; ++j) {
                int c = wc + j * 16 + fr;
                int chunk = (ks * 4 + kg) ^ (c & 7);
                b[j] = *(const bf16x8*)((const char*)Bs + c * 128 + chunk * 16);
            }
            #pragma unroll
            for (int i = 0; i < 4; ++i)
                #pragma unroll
                for (int j = 0; j < 4; ++j)
                    acc[i][j] = __builtin_amdgcn_mfma_f32_16x16x32_bf16(
                        a[i], b[j], acc[i][j], 0, 0, 0);
        }
        __syncthreads();
    }

    if constexpr (MODE == 1) {
        // f32 out: 16 lanes x 4B = 64B lines, coalesced enough.
        #pragma unroll
        for (int j = 0; j < 4; ++j) {
            int gcol = col0 + wc + j * 16 + fr;
            float bj = bias[gcol];
            #pragma unroll
            for (int i = 0; i < 4; ++i) {
                #pragma unroll
                for (int r = 0; r < 4; ++r) {
                    int grow = row0 + wr + i * 16 + kg * 4 + r;
                    if (grow >= n) continue;
                    outf[(size_t)grow * 256 + gcol] = acc[i][j][r] + bj;
                }
            }
        }
        return;
    }

    // ---- MODE 0 epilogue: pack to LDS, then coalesced 256B row bursts ----
    char* sb = (char*)SH;
    const bool isf8 = (col0 >= 256 && col0 < 512);   // k tile -> fp8
    const float sc = (col0 < 256) ? scale : 1.f;

    #pragma unroll
    for (int j = 0; j < 4; ++j) {
        int cw = wc + j * 16 + fr;                   // local col 0..127
        float bj = bias[col0 + cw];
        #pragma unroll
        for (int i = 0; i < 4; ++i) {
            #pragma unroll
            for (int r = 0; r < 4; ++r) {
                int lrow = wr + i * 16 + kg * 4 + r; // local row 0..127
                float val = (acc[i][j][r] + bj) * sc;
                if (isf8) {
                    int u = cw >> 4;
                    sb[lrow * 128 + ((u ^ (lrow & 7)) << 4) + (cw & 15)] = f2fp8(val);
                } else {
                    int u = cw >> 3;
                    *(ushort*)(sb + lrow * 256 + ((u ^ (lrow & 7)) << 4) +
                               ((cw & 7) << 1)) = f2bf(val);
                }
            }
        }
    }
    __syncthreads();

    if (isf8) {
        // 128 rows x 128B = 16KB, 4 passes; 8 lanes = one 128B row segment
        int seg = col0 - 256;     // 0 or 128
        #pragma unroll
        for (int pass = 0; pass < 4; ++pass) {
            int g = pass * 256 + tid;
            int lrow = g >> 3, u = g & 7;
            uint4 d = *(const uint4*)(sb + lrow * 128 + ((u ^ (lrow & 7)) << 4));
            int grow = row0 + lrow;
            if (grow < n)
                *(uint4*)((char*)kv + (size_t)grow * 768 + seg + u * 16) = d;
        }
    } else {
        // 128 rows x 256B = 32KB, 8 passes; 16 lanes = one 256B row segment
        char* dst; size_t stride; int seg;
        if (col0 < 256) { dst = (char*)qb; stride = 512; seg = col0 * 2; }
        else            { dst = (char*)kv; stride = 768; seg = 256 + (col0 - 512) * 2; }
        #pragma unroll
        for (int pass = 0; pass < 8; ++pass) {
            int g = pass * 256 + tid;
            int lrow = g >> 4, u = g & 15;
            uint4 d = *(const uint4*)(sb + lrow * 256 + ((u ^ (lrow & 7)) << 4));
            int grow = row0 + lrow;
            if (grow < n)
                *(uint4*)(dst + (size_t)grow * stride + seg + u * 16) = d;
        }
    }
}

// CSR row pointers from sorted row[]: row_ptr[i] = lower_bound(row, i)
__global__ __launch_bounds__(256) void build_row_ptr(
    const int* __restrict__ row, int* __restrict__ row_ptr, int n, int E)
{
    int i = blockIdx.x * 256 + threadIdx.x;
    if (i > n) return;
    int lo = 0, hi = E;
    while (lo < hi) {
        int mid = (lo + hi) >> 1;
        if (row[mid] < i) lo = mid + 1; else hi = mid;
    }
    row_ptr[i] = lo;
}

// Fused SDDMM + softmax + SpMM. One wave per dst node.
// kv row (768B): k fp8 e4m3 [0,256) + v bf16 [256,768).
__global__ __launch_bounds__(256) void fused_attn(
    const ushort* __restrict__ qb, const uchar* __restrict__ kv,
    const int* __restrict__ col, const int* __restrict__ row_ptr,
    ushort* __restrict__ agg, int n)
{
    int node = blockIdx.x * 4 + (threadIdx.x >> 6);
    if (node >= n) return;
    int lane = threadIdx.x & 63;
    int p0 = row_ptr[node], p1 = row_ptr[node + 1];

    const int slot = lane >> 4;          // 0..3 edge slot
    const int l16 = lane & 15;           // (head, half) index
    const int qoff = l16 * 32;           // byte offset into 512B bf16 q row

    float qf[16];
    {
        const char* qbp = (const char*)qb + (size_t)node * 512 + qoff;
        uint4 q0 = *(const uint4*)qbp;
        uint4 q1 = *(const uint4*)(qbp + 16);
        qf[0] = bflo(q0.x); qf[1] = bfhi(q0.x);
        qf[2] = bflo(q0.y); qf[3] = bfhi(q0.y);
        qf[4] = bflo(q0.z); qf[5] = bfhi(q0.z);
        qf[6] = bflo(q0.w); qf[7] = bfhi(q0.w);
        qf[8] = bflo(q1.x); qf[9] = bfhi(q1.x);
        qf[10] = bflo(q1.y); qf[11] = bfhi(q1.y);
        qf[12] = bflo(q1.z); qf[13] = bfhi(q1.z);
        qf[14] = bflo(q1.w); qf[15] = bfhi(q1.w);
    }

    float denom = 0.f;
    float acc[16] = {};

#define ISSUE(IDX, K, V0, V1)                                                  \
    do {                                                                       \
        int src_ = __shfl(cl, (IDX));                                          \
        const char* b_ = (const char*)kv + (size_t)src_ * 768;                 \
        K  = *(const uint4*)(b_ + l16 * 16);                                   \
        V0 = *(const uint4*)(b_ + 256 + l16 * 32);                             \
        V1 = *(const uint4*)(b_ + 272 + l16 * 32);                             \
    } while (0)

#define CONSUME(VALID, K, V0, V1)                                              \
    do {                                                                       \
        float kf_[16];                                                         \
        fp8x4_to_f32(K.x, kf_); fp8x4_to_f32(K.y, kf_ + 4);                    \
        fp8x4_to_f32(K.z, kf_ + 8); fp8x4_to_f32(K.w, kf_ + 12);               \
        float sp_ = 0.f;                                                       \
        _Pragma("unroll")                                                      \
        for (int i_ = 0; i_ < 16; ++i_) sp_ = fmaf(qf[i_], kf_[i_], sp_);      \
        float s_ = sp_ + __shfl_xor(sp_, 1);                                   \
        float p_ = (VALID) ? __expf(s_) : 0.f;                                 \
        denom += p_;                                                           \
        acc[0]  = fmaf(p_, bflo(V0.x), acc[0]);                                \
        acc[1]  = fmaf(p_, bfhi(V0.x), acc[1]);                                \
        acc[2]  = fmaf(p_, bflo(V0.y), acc[2]);                                \
        acc[3]  = fmaf(p_, bfhi(V0.y), acc[3]);                                \
        acc[4]  = fmaf(p_, bflo(V0.z), acc[4]);                                \
        acc[5]  = fmaf(p_, bfhi(V0.z), acc[5]);                                \
        acc[6]  = fmaf(p_, bflo(V0.w), acc[6]);                                \
        acc[7]  = fmaf(p_, bfhi(V0.w), acc[7]);                                \
        acc[8]  = fmaf(p_, bflo(V1.x), acc[8]);                                \
        acc[9]  = fmaf(p_, bfhi(V1.x), acc[9]);                                \
        acc[10] = fmaf(p_, bflo(V1.y), acc[10]);                               \
        acc[11] = fmaf(p_, bfhi(V1.y), acc[11]);                               \
        acc[12] = fmaf(p_, bflo(V1.z), acc[12]);                               \
        acc[13] = fmaf(p_, bfhi(V1.z), acc[13]);                               \
        acc[14] = fmaf(p_, bflo(V1.w), acc[14]);                               \
        acc[15] = fmaf(p_, bfhi(V1.w), acc[15]);                               \
    } while (0)

    for (int bbase = p0; bbase < p1; bbase += 64) {
        int bd = min(64, p1 - bbase);
        int cl = (lane < bd) ? col[bbase + lane] : 0;
        int nch = (bd + 3) >> 2;

        uint4 kA, vA0, vA1, kB, vB0, vB1;
        ISSUE(slot, kA, vA0, vA1);
        int c = 0;
        for (;;) {
            if (c + 1 < nch) ISSUE((c + 1) * 4 + slot, kB, vB0, vB1);
            CONSUME(c * 4 + slot < bd, kA, vA0, vA1);
            if (++c >= nch) break;
            if (c + 1 < nch) ISSUE((c + 1) * 4 + slot, kA, vA0, vA1);
            CONSUME(c * 4 + slot < bd, kB, vB0, vB1);
            if (++c >= nch) break;
        }
    }
#undef ISSUE
#undef CONSUME

    #pragma unroll
    for (int i = 0; i < 16; ++i) {
        acc[i] += __shfl_xor(acc[i], 16);
        acc[i] += __shfl_xor(acc[i], 32);
    }
    denom += __shfl_xor(denom, 16);
    denom += __shfl_xor(denom, 32);

    if (slot == 0) {
        float inv = denom > 0.f ? 1.f / denom : 0.f;
        uint o[8];
        #pragma unroll
        for (int i = 0; i < 8; ++i)
            o[i] = (uint)f2bf(acc[2 * i] * inv) |
                   ((uint)f2bf(acc[2 * i + 1] * inv) << 16);
        char* ob = (char*)agg + (size_t)node * 512 + qoff;
        *(uint4*)ob        = make_uint4(o[0], o[1], o[2], o[3]);
        *(uint4*)(ob + 16) = make_uint4(o[4], o[5], o[6], o[7]);
    }
}

extern "C" void kernel_launch(void* const* d_in, const int* in_sizes, int n_in,
                              void* d_out, int out_size, void* d_ws, size_t ws_size,
                              hipStream_t stream)
{
    const float* h  = (const float*)d_in[0];
    const int*   row = (const int*)d_in[1];
    const int*   col = (const int*)d_in[2];
    const float* Wq = (const float*)d_in[3];
    const float* bq = (const float*)d_in[4];
    const float* Wk = (const float*)d_in[5];
    const float* bk = (const float*)d_in[6];
    const float* Wv = (const float*)d_in[7];
    const float* bv = (const float*)d_in[8];
    const float* Wo = (const float*)d_in[9];
    const float* bo = (const float*)d_in[10];
    float* out = (float*)d_out;

    const int n = in_sizes[0] / 256;
    const int E = in_sizes[1];
    const size_t NC = (size_t)n * 256;

    char* base = (char*)d_ws;
    ushort* qbb  = (ushort*)(base);                 // NC*2 B
    uchar*  kv   = (uchar*)(base + NC * 2);         // n*768 B
    ushort* hb   = (ushort*)(base + NC * 2 + (size_t)n * 768);   // NC*2
    ushort* aggb = (ushort*)(base + NC * 4 + (size_t)n * 768);   // NC*2
    ushort* Wall = (ushort*)(base + NC * 6 + (size_t)n * 768);   // 384KB
    ushort* Wot  = Wall + 768 * 256;                // 128KB
    float*  ball = (float*)(Wot + 65536);           // 3KB
    int* row_ptr = (int*)(ball + 768);

    const float scaling = 0.17677669529663687f;  // 32^-0.5

    dim3 blk(256);
    convert_bf16<<<dim3((int)((NC / 4 + 255) / 256)), blk, 0, stream>>>(h, hb, NC);
    prep_w<<<dim3(257, 4), blk, 0, stream>>>(Wq, Wk, Wv, Wo, bq, bk, bv,
                                             Wall, Wot, ball);
    build_row_ptr<<<dim3((n + 256) / 256), blk, 0, stream>>>(row, row_ptr, n, E);

    const int mtiles = (n + 127) / 128;
    gemm_mfma_lds<0><<<dim3(6, mtiles), blk, 0, stream>>>(
        hb, Wall, ball, qbb, kv, nullptr, n, scaling);

    fused_attn<<<dim3((n + 3) / 4), blk, 0, stream>>>(
        qbb, kv, col, row_ptr, aggb, n);

    gemm_mfma_lds<1><<<dim3(2, mtiles), blk, 0, stream>>>(
        aggb, Wot, bo, nullptr, nullptr, out, n, 1.f);
}